// Round 7
// baseline (2521.295 us; speedup 1.0000x reference)
//
#include <hip/hip_runtime.h>
#include <hip/hip_bf16.h>

#define GN 50000
#define GE 800000
#define FIN 128
#define GH 256
#define GB 128
#define NCLS 10
#define GSCALE 3
#define GNNZ 1200000
#define NSEG (GSCALE * GB)  // 384

// wavelet+pool col-bucket config
#define SLW 32                       // feature slice width
#define NSLICE (GH / SLW)            // 8
#define NCHUNK 64                    // col chunks
#define CPC ((GN + NCHUNK - 1) / NCHUNK)  // 782

// ---------------- degree / dinv ----------------
__global__ __launch_bounds__(256) void deg_count_kernel(const int* __restrict__ dst,
                                                        int* __restrict__ deg) {
  int i = blockIdx.x * 256 + threadIdx.x;
  if (i < GE) atomicAdd(&deg[dst[i]], 1);
}

__global__ __launch_bounds__(256) void dinv_kernel(const int* __restrict__ deg,
                                                   float* __restrict__ dinv) {
  int i = blockIdx.x * 256 + threadIdx.x;
  if (i < GN) dinv[i] = 1.0f / sqrtf((float)(deg[i] + 1));  // self-loop => deg+1 >= 1
}

// ---------------- hierarchical exclusive scan (n up to GN) ----------------
__global__ __launch_bounds__(256) void scan1_kernel(const int* __restrict__ in,
                                                    int* __restrict__ out,
                                                    int* __restrict__ btot, int n) {
  __shared__ int sh[256];
  int b = blockIdx.x, tid = threadIdx.x;
  int i = b * 256 + tid;
  int v = (i < n) ? in[i] : 0;
  sh[tid] = v;
  __syncthreads();
  for (int ofs = 1; ofs < 256; ofs <<= 1) {
    int t = (tid >= ofs) ? sh[tid - ofs] : 0;
    __syncthreads();
    sh[tid] += t;
    __syncthreads();
  }
  if (i < n) out[i] = sh[tid] - v;  // block-local exclusive
  if (tid == 255) btot[b] = sh[255];
}

__global__ __launch_bounds__(256) void scan2_kernel(int* __restrict__ btot, int nb) {
  __shared__ int sh[256];
  int tid = threadIdx.x;
  int v = (tid < nb) ? btot[tid] : 0;
  sh[tid] = v;
  __syncthreads();
  for (int ofs = 1; ofs < 256; ofs <<= 1) {
    int t = (tid >= ofs) ? sh[tid - ofs] : 0;
    __syncthreads();
    sh[tid] += t;
    __syncthreads();
  }
  if (tid < nb) btot[tid] = sh[tid] - v;  // exclusive block bases
}

__global__ __launch_bounds__(256) void scan3_kernel(int* __restrict__ out,
                                                    const int* __restrict__ btot,
                                                    int n, int total) {
  int b = blockIdx.x, tid = threadIdx.x;
  int i = b * 256 + tid;
  if (i < n) out[i] += btot[b];
  if (i == 0) out[n] = total;
}

// ---------------- CSR fill (bucket edges by dst) ----------------
__global__ __launch_bounds__(256) void csr_fill_kernel(const int* __restrict__ src,
                                                       const int* __restrict__ dst,
                                                       int* __restrict__ cur,
                                                       int* __restrict__ csr_src) {
  int i = blockIdx.x * 256 + threadIdx.x;
  if (i < GE) {
    int j = atomicAdd(&cur[dst[i]], 1);
    csr_src[j] = src[i];
  }
}

// ---------------- col bucketing for wavelet+pool ----------------
__device__ __forceinline__ int seg_of(int row, const int* __restrict__ batch) {
  int sc = row / GN;
  int node = row - sc * GN;
  return sc * GB + batch[node];
}

__global__ __launch_bounds__(256) void col_cnt_kernel(const int* __restrict__ cols,
                                                      int* __restrict__ ccnt) {
  int i = blockIdx.x * 256 + threadIdx.x;
  if (i < GNNZ) atomicAdd(&ccnt[cols[i]], 1);
}

__global__ __launch_bounds__(256) void col_fill_kernel(const int* __restrict__ rows,
                                                       const int* __restrict__ cols,
                                                       const float* __restrict__ d,
                                                       const int* __restrict__ batch,
                                                       int* __restrict__ ccur,
                                                       int* __restrict__ bseg,
                                                       float* __restrict__ bd) {
  int i = blockIdx.x * 256 + threadIdx.x;
  if (i < GNNZ) {
    int j = atomicAdd(&ccur[cols[i]], 1);
    bseg[j] = seg_of(rows[i], batch);
    bd[j] = d[i];
  }
}

// ---------------- fp32 GEMM: C[M][256] = A[M][K] @ W[K][256] ----------------
template <int K>
__global__ __launch_bounds__(256) void gemm_kernel(const float* __restrict__ A,
                                                   const float* __restrict__ W,
                                                   float* __restrict__ C, int M) {
  __shared__ float As[16][64];  // As[k][r] = A[row0+r][kk+k]
  __shared__ float Bs[16][64];  // Bs[k][c] = W[kk+k][col0+c]
  int tid = threadIdx.x;
  int col0 = blockIdx.x * 64;
  int row0 = blockIdx.y * 64;
  float acc[4][4] = {};
  int ar = tid >> 2, akq = tid & 3;    // A stage: row ar, float4 group akq
  int bkr = tid >> 4, bcq = tid & 15;  // B stage
  int ty = tid >> 4, tx = tid & 15;
  for (int kk = 0; kk < K; kk += 16) {
    int arow = row0 + ar;
    if (arow >= M) arow = M - 1;
    float4 av = *(const float4*)&A[(size_t)arow * K + kk + akq * 4];
    float4 bv = *(const float4*)&W[(size_t)(kk + bkr) * GH + col0 + bcq * 4];
    __syncthreads();
    As[akq * 4 + 0][ar] = av.x;
    As[akq * 4 + 1][ar] = av.y;
    As[akq * 4 + 2][ar] = av.z;
    As[akq * 4 + 3][ar] = av.w;
    *(float4*)&Bs[bkr][bcq * 4] = bv;
    __syncthreads();
#pragma unroll
    for (int k = 0; k < 16; ++k) {
      float4 a = *(const float4*)&As[k][ty * 4];
      float4 b = *(const float4*)&Bs[k][tx * 4];
      acc[0][0] += a.x * b.x; acc[0][1] += a.x * b.y; acc[0][2] += a.x * b.z; acc[0][3] += a.x * b.w;
      acc[1][0] += a.y * b.x; acc[1][1] += a.y * b.y; acc[1][2] += a.y * b.z; acc[1][3] += a.y * b.w;
      acc[2][0] += a.z * b.x; acc[2][1] += a.z * b.y; acc[2][2] += a.z * b.z; acc[2][3] += a.z * b.w;
      acc[3][0] += a.w * b.x; acc[3][1] += a.w * b.y; acc[3][2] += a.w * b.z; acc[3][3] += a.w * b.w;
    }
  }
#pragma unroll
  for (int i = 0; i < 4; ++i) {
    int r = row0 + ty * 4 + i;
    if (r < M) {
      float4 v = make_float4(acc[i][0], acc[i][1], acc[i][2], acc[i][3]);
      *(float4*)&C[(size_t)r * GH + col0 + tx * 4] = v;
    }
  }
}

// ------------- GCN aggregation: gather + self-loop + bias + relu -------------
__global__ __launch_bounds__(256) void agg_kernel(const float* __restrict__ m,
                                                  const float* __restrict__ dinv,
                                                  const int* __restrict__ off,
                                                  const int* __restrict__ srcs,
                                                  const float* __restrict__ bias,
                                                  float* __restrict__ out) {
  int node = blockIdx.x * 4 + (threadIdx.x >> 6);
  if (node >= GN) return;
  int lane = threadIdx.x & 63;
  float4 acc = *(const float4*)&bias[lane * 4];
  float di = dinv[node];
  float w0 = di * di;  // self-loop norm
  float4 mv = *(const float4*)&m[(size_t)node * GH + lane * 4];
  acc.x += w0 * mv.x; acc.y += w0 * mv.y; acc.z += w0 * mv.z; acc.w += w0 * mv.w;
  int e0 = off[node], e1 = off[node + 1];
  int e = e0;
  for (; e + 2 <= e1; e += 2) {  // unroll-by-2: two row loads in flight
    int s0 = srcs[e], s1 = srcs[e + 1];
    float w0a = di * dinv[s0];
    float w1a = di * dinv[s1];
    float4 v0 = *(const float4*)&m[(size_t)s0 * GH + lane * 4];
    float4 v1 = *(const float4*)&m[(size_t)s1 * GH + lane * 4];
    acc.x += w0a * v0.x + w1a * v1.x;
    acc.y += w0a * v0.y + w1a * v1.y;
    acc.z += w0a * v0.z + w1a * v1.z;
    acc.w += w0a * v0.w + w1a * v1.w;
  }
  if (e < e1) {
    int s = srcs[e];
    float w = di * dinv[s];
    float4 v = *(const float4*)&m[(size_t)s * GH + lane * 4];
    acc.x += w * v.x; acc.y += w * v.y; acc.z += w * v.z; acc.w += w * v.w;
  }
  acc.x = fmaxf(acc.x, 0.f); acc.y = fmaxf(acc.y, 0.f);
  acc.z = fmaxf(acc.z, 0.f); acc.w = fmaxf(acc.w, 0.f);
  *(float4*)&out[(size_t)node * GH + lane * 4] = acc;
}

// ------- wavelet+pool: stream h by col, scatter into LDS seg accumulators -------
// grid (NCHUNK, NSLICE), block 256. LDS acc[NSEG][SLW] = 48KB -> 3 blocks/CU.
// Each h element is read exactly ONCE across the whole grid (51 MB vs 1.23 GB).
__global__ __launch_bounds__(256) void pooled2_kernel(const float* __restrict__ h,
                                                      const int* __restrict__ coff,
                                                      const int* __restrict__ bseg,
                                                      const float* __restrict__ bd,
                                                      float* __restrict__ pp) {
  __shared__ float acc[NSEG * SLW];  // 12288 floats = 48 KB
  int tid = threadIdx.x;
  int chunk = blockIdx.x, slice = blockIdx.y;
#pragma unroll
  for (int t = tid; t < NSEG * SLW; t += 256) acc[t] = 0.f;
  __syncthreads();

  int wid = tid >> 6;
  int lane = tid & 63;
  int sub = lane >> 5;   // which of the wave's 2 columns
  int f = lane & 31;     // feature within slice
  int c0base = chunk * CPC;
  int cend = c0base + CPC;
  if (cend > GN) cend = GN;
  for (int c0 = c0base + wid * 2; c0 < cend; c0 += 8) {
    int c = c0 + sub;
    bool valid = c < cend;
    float hv = valid ? h[(size_t)c * GH + slice * SLW + f] : 0.f;
    int p0 = valid ? coff[c] : 0;
    int p1 = valid ? coff[c + 1] : 0;
    for (int p = p0; p < p1; ++p) {  // ~24 iters avg, divergent between subs
      int s = bseg[p];
      float dv = bd[p];
      atomicAdd(&acc[s * SLW + f], dv * hv);  // ds_add_f32, 2 lanes/bank
    }
  }
  __syncthreads();
  float* dst = &pp[((size_t)slice * NCHUNK + chunk) * (NSEG * SLW)];
#pragma unroll
  for (int t = tid; t < NSEG * SLW; t += 256) dst[t] = acc[t];
}

// reduce partials: pooled[seg][slice*SLW+f] = sum over chunks
__global__ __launch_bounds__(256) void pool_reduce_kernel(const float* __restrict__ pp,
                                                          float* __restrict__ pooled) {
  int seg = blockIdx.x;
  int tid = threadIdx.x;       // 256 feats
  int slice = tid >> 5;        // tid / SLW
  int f = tid & 31;
  float v = 0.f;
  for (int ch = 0; ch < NCHUNK; ++ch) {
    v += pp[((size_t)slice * NCHUNK + ch) * (NSEG * SLW) + seg * SLW + f];
  }
  pooled[(size_t)seg * GH + tid] = v;
}

// ---------------- FC head ----------------
__global__ __launch_bounds__(256) void fc1_kernel(const float* __restrict__ pooled,
                                                  const float* __restrict__ w,
                                                  const float* __restrict__ b,
                                                  float* __restrict__ z1) {
  __shared__ float vin[GSCALE * GH];  // 768
  int g = blockIdx.x, tid = threadIdx.x;
#pragma unroll
  for (int it = 0; it < GSCALE; ++it)
    vin[it * GH + tid] = pooled[(size_t)(it * GB + g) * GH + tid];
  __syncthreads();
  float acc = b[tid];
  for (int j = 0; j < GSCALE * GH; ++j) acc += vin[j] * w[(size_t)j * GH + tid];
  z1[(size_t)g * GH + tid] = fmaxf(acc, 0.f);
}

__global__ __launch_bounds__(128) void fc2_kernel(const float* __restrict__ z1,
                                                  const float* __restrict__ w,
                                                  const float* __restrict__ b,
                                                  float* __restrict__ z2) {
  __shared__ float vin[GH];
  int g = blockIdx.x, tid = threadIdx.x;  // 128 threads
  vin[tid] = z1[(size_t)g * GH + tid];
  vin[128 + tid] = z1[(size_t)g * GH + 128 + tid];
  __syncthreads();
  float acc = b[tid];
  for (int j = 0; j < GH; ++j) acc += vin[j] * w[(size_t)j * 128 + tid];
  z2[(size_t)g * 128 + tid] = fmaxf(acc, 0.f);
}

__global__ __launch_bounds__(128) void fc3_kernel(const float* __restrict__ z2,
                                                  const float* __restrict__ w,
                                                  const float* __restrict__ b,
                                                  float* __restrict__ out) {
  int g = threadIdx.x;  // one thread per graph, 1 block of 128
  float logit[NCLS];
#pragma unroll
  for (int o = 0; o < NCLS; ++o) logit[o] = b[o];
  for (int k = 0; k < 128; ++k) {
    float zv = z2[(size_t)g * 128 + k];
#pragma unroll
    for (int o = 0; o < NCLS; ++o) logit[o] += zv * w[k * NCLS + o];
  }
  float mx = logit[0];
#pragma unroll
  for (int o = 1; o < NCLS; ++o) mx = fmaxf(mx, logit[o]);
  float lse = 0.f;
#pragma unroll
  for (int o = 0; o < NCLS; ++o) lse += expf(logit[o] - mx);
  lse = logf(lse);
#pragma unroll
  for (int o = 0; o < NCLS; ++o) out[(size_t)g * NCLS + o] = logit[o] - mx - lse;
}

// ---------------- launch ----------------
static inline size_t alignup(size_t x) { return (x + 1023) & ~(size_t)1023; }

extern "C" void kernel_launch(void* const* d_in, const int* in_sizes, int n_in,
                              void* d_out, int out_size, void* d_ws, size_t ws_size,
                              hipStream_t stream) {
  const float* x      = (const float*)d_in[0];
  const float* W1     = (const float*)d_in[1];
  const float* b1     = (const float*)d_in[2];
  const float* W2     = (const float*)d_in[3];
  const float* b2     = (const float*)d_in[4];
  const float* W3     = (const float*)d_in[5];
  const float* b3     = (const float*)d_in[6];
  const float* fc1w   = (const float*)d_in[7];
  const float* fc1b   = (const float*)d_in[8];
  const float* fc2w   = (const float*)d_in[9];
  const float* fc2b   = (const float*)d_in[10];
  const float* fc3w   = (const float*)d_in[11];
  const float* fc3b   = (const float*)d_in[12];
  const float* dval   = (const float*)d_in[13];
  const int* eidx     = (const int*)d_in[14];
  const int* batch    = (const int*)d_in[15];
  const int* didx     = (const int*)d_in[16];
  float* out          = (float*)d_out;

  const int* esrc = eidx;             // edge_index[0]
  const int* edst = eidx + GE;        // edge_index[1]
  const int* nzrow = didx;            // d_index[0]
  const int* nzcol = didx + GNNZ;     // d_index[1]

  // workspace carve-up
  char* ws = (char*)d_ws;
  size_t o = 0;
  auto take = [&](size_t bytes) { char* p = ws + o; o += alignup(bytes); return p; };
  int*   deg     = (int*)take(GN * 4);
  int*   off     = (int*)take((GN + 1) * 4);
  int*   cur     = (int*)take(GN * 4);
  int*   btot    = (int*)take(256 * 4);
  float* dinv    = (float*)take(GN * 4);
  int*   csr_src = (int*)take(GE * 4);
  int*   ccnt    = (int*)take(GN * 4);
  int*   coff    = (int*)take((GN + 1) * 4);
  int*   ccur    = (int*)take(GN * 4);
  int*   bseg    = (int*)take((size_t)GNNZ * 4);
  float* bd      = (float*)take((size_t)GNNZ * 4);
  float* mbuf    = (float*)take((size_t)GN * GH * 4);
  float* hA      = (float*)take((size_t)GN * GH * 4);
  float* hB      = (float*)take((size_t)GN * GH * 4);
  float* pooled  = (float*)take((size_t)NSEG * GH * 4);
  float* z1      = (float*)take((size_t)GB * GH * 4);
  float* z2      = (float*)take((size_t)GB * 128 * 4);
  float* pp      = mbuf;  // alias: partials (25.2 MB) live in mbuf, free after last agg
  (void)ws_size; (void)n_in; (void)in_sizes; (void)out_size;

  const int NB = (GN + 255) / 256;  // 196

  // ---- graph prep (once per call) ----
  hipMemsetAsync(deg, 0, GN * 4, stream);
  hipMemsetAsync(ccnt, 0, GN * 4, stream);

  deg_count_kernel<<<GE / 256, 256, 0, stream>>>(edst, deg);
  dinv_kernel<<<NB, 256, 0, stream>>>(deg, dinv);
  scan1_kernel<<<NB, 256, 0, stream>>>(deg, off, btot, GN);
  scan2_kernel<<<1, 256, 0, stream>>>(btot, NB);
  scan3_kernel<<<NB, 256, 0, stream>>>(off, btot, GN, GE);
  hipMemcpyAsync(cur, off, GN * 4, hipMemcpyDeviceToDevice, stream);
  csr_fill_kernel<<<GE / 256, 256, 0, stream>>>(esrc, edst, cur, csr_src);

  // col buckets for wavelet+pool
  col_cnt_kernel<<<(GNNZ + 255) / 256, 256, 0, stream>>>(nzcol, ccnt);
  scan1_kernel<<<NB, 256, 0, stream>>>(ccnt, coff, btot, GN);
  scan2_kernel<<<1, 256, 0, stream>>>(btot, NB);
  scan3_kernel<<<NB, 256, 0, stream>>>(coff, btot, GN, GNNZ);
  hipMemcpyAsync(ccur, coff, GN * 4, hipMemcpyDeviceToDevice, stream);
  col_fill_kernel<<<(GNNZ + 255) / 256, 256, 0, stream>>>(nzrow, nzcol, dval, batch,
                                                          ccur, bseg, bd);

  // ---- 3 GCN layers ----
  dim3 ggrid(GH / 64, (GN + 63) / 64);
  gemm_kernel<FIN><<<ggrid, 256, 0, stream>>>(x, W1, mbuf, GN);
  agg_kernel<<<(GN + 3) / 4, 256, 0, stream>>>(mbuf, dinv, off, csr_src, b1, hA);
  gemm_kernel<GH><<<ggrid, 256, 0, stream>>>(hA, W2, mbuf, GN);
  agg_kernel<<<(GN + 3) / 4, 256, 0, stream>>>(mbuf, dinv, off, csr_src, b2, hB);
  gemm_kernel<GH><<<ggrid, 256, 0, stream>>>(hB, W3, mbuf, GN);
  agg_kernel<<<(GN + 3) / 4, 256, 0, stream>>>(mbuf, dinv, off, csr_src, b3, hA);

  // ---- fused wavelet + pooling (hA holds final node features; pp aliases mbuf) ----
  pooled2_kernel<<<dim3(NCHUNK, NSLICE), 256, 0, stream>>>(hA, coff, bseg, bd, pp);
  pool_reduce_kernel<<<NSEG, 256, 0, stream>>>(pp, pooled);

  // ---- FC head ----
  fc1_kernel<<<GB, 256, 0, stream>>>(pooled, fc1w, fc1b, z1);
  fc2_kernel<<<GB, 128, 0, stream>>>(z1, fc2w, fc2b, z2);
  fc3_kernel<<<1, 128, 0, stream>>>(z2, fc3w, fc3b, out);
}

// Round 9
// 2504.278 us; speedup vs baseline: 1.0068x; 1.0068x over previous
//
#include <hip/hip_runtime.h>
#include <hip/hip_bf16.h>

#define GN 50000
#define GE 800000
#define FIN 128
#define GH 256
#define GB 128
#define NCLS 10
#define GSCALE 3
#define GNNZ 1200000
#define NSEG (GSCALE * GB)  // 384

// wavelet+pool config: nonzero-parallel, col-sorted, LDS seg accumulators
#define SLW 32                            // feature slice width
#define NSLICE (GH / SLW)                 // 8
#define NCHB 96                           // nnz chunks (3 blocks/CU * 256 CU / NSLICE)
#define PPB ((GNNZ + NCHB - 1) / NCHB)    // 12500 nnz per block

// ---------------- degree / dinv ----------------
__global__ __launch_bounds__(256) void deg_count_kernel(const int* __restrict__ dst,
                                                        int* __restrict__ deg) {
  int i = blockIdx.x * 256 + threadIdx.x;
  if (i < GE) atomicAdd(&deg[dst[i]], 1);
}

__global__ __launch_bounds__(256) void dinv_kernel(const int* __restrict__ deg,
                                                   float* __restrict__ dinv) {
  int i = blockIdx.x * 256 + threadIdx.x;
  if (i < GN) dinv[i] = 1.0f / sqrtf((float)(deg[i] + 1));  // self-loop => deg+1 >= 1
}

// ---------------- hierarchical exclusive scan (n up to GN) ----------------
__global__ __launch_bounds__(256) void scan1_kernel(const int* __restrict__ in,
                                                    int* __restrict__ out,
                                                    int* __restrict__ btot, int n) {
  __shared__ int sh[256];
  int b = blockIdx.x, tid = threadIdx.x;
  int i = b * 256 + tid;
  int v = (i < n) ? in[i] : 0;
  sh[tid] = v;
  __syncthreads();
  for (int ofs = 1; ofs < 256; ofs <<= 1) {
    int t = (tid >= ofs) ? sh[tid - ofs] : 0;
    __syncthreads();
    sh[tid] += t;
    __syncthreads();
  }
  if (i < n) out[i] = sh[tid] - v;  // block-local exclusive
  if (tid == 255) btot[b] = sh[255];
}

__global__ __launch_bounds__(256) void scan2_kernel(int* __restrict__ btot, int nb) {
  __shared__ int sh[256];
  int tid = threadIdx.x;
  int v = (tid < nb) ? btot[tid] : 0;
  sh[tid] = v;
  __syncthreads();
  for (int ofs = 1; ofs < 256; ofs <<= 1) {
    int t = (tid >= ofs) ? sh[tid - ofs] : 0;
    __syncthreads();
    sh[tid] += t;
    __syncthreads();
  }
  if (tid < nb) btot[tid] = sh[tid] - v;  // exclusive block bases
}

__global__ __launch_bounds__(256) void scan3_kernel(int* __restrict__ out,
                                                    const int* __restrict__ btot,
                                                    int n, int total) {
  int b = blockIdx.x, tid = threadIdx.x;
  int i = b * 256 + tid;
  if (i < n) out[i] += btot[b];
  if (i == 0) out[n] = total;
}

// ---------------- CSR fill (bucket edges by dst) ----------------
__global__ __launch_bounds__(256) void csr_fill_kernel(const int* __restrict__ src,
                                                       const int* __restrict__ dst,
                                                       int* __restrict__ cur,
                                                       int* __restrict__ csr_src) {
  int i = blockIdx.x * 256 + threadIdx.x;
  if (i < GE) {
    int j = atomicAdd(&cur[dst[i]], 1);
    csr_src[j] = src[i];
  }
}

// ---------------- col bucketing for wavelet+pool ----------------
__device__ __forceinline__ int seg_of(int row, const int* __restrict__ batch) {
  int sc = row / GN;
  int node = row - sc * GN;
  return sc * GB + batch[node];
}

__global__ __launch_bounds__(256) void col_cnt_kernel(const int* __restrict__ cols,
                                                      int* __restrict__ ccnt) {
  int i = blockIdx.x * 256 + threadIdx.x;
  if (i < GNNZ) atomicAdd(&ccnt[cols[i]], 1);
}

// pk[j] = { col | (seg<<16), float_bits(d) }, sorted by col. col<50000<2^16, seg<384.
__global__ __launch_bounds__(256) void col_fill_kernel(const int* __restrict__ rows,
                                                       const int* __restrict__ cols,
                                                       const float* __restrict__ d,
                                                       const int* __restrict__ batch,
                                                       int* __restrict__ ccur,
                                                       int2* __restrict__ pk) {
  int i = blockIdx.x * 256 + threadIdx.x;
  if (i < GNNZ) {
    int c = cols[i];
    int j = atomicAdd(&ccur[c], 1);
    int s = seg_of(rows[i], batch);
    pk[j] = make_int2(c | (s << 16), __float_as_int(d[i]));
  }
}

// ---------------- fp32 GEMM: C[M][256] = A[M][K] @ W[K][256] ----------------
template <int K>
__global__ __launch_bounds__(256) void gemm_kernel(const float* __restrict__ A,
                                                   const float* __restrict__ W,
                                                   float* __restrict__ C, int M) {
  __shared__ float As[16][64];  // As[k][r] = A[row0+r][kk+k]
  __shared__ float Bs[16][64];  // Bs[k][c] = W[kk+k][col0+c]
  int tid = threadIdx.x;
  int col0 = blockIdx.x * 64;
  int row0 = blockIdx.y * 64;
  float acc[4][4] = {};
  int ar = tid >> 2, akq = tid & 3;    // A stage: row ar, float4 group akq
  int bkr = tid >> 4, bcq = tid & 15;  // B stage
  int ty = tid >> 4, tx = tid & 15;
  for (int kk = 0; kk < K; kk += 16) {
    int arow = row0 + ar;
    if (arow >= M) arow = M - 1;
    float4 av = *(const float4*)&A[(size_t)arow * K + kk + akq * 4];
    float4 bv = *(const float4*)&W[(size_t)(kk + bkr) * GH + col0 + bcq * 4];
    __syncthreads();
    As[akq * 4 + 0][ar] = av.x;
    As[akq * 4 + 1][ar] = av.y;
    As[akq * 4 + 2][ar] = av.z;
    As[akq * 4 + 3][ar] = av.w;
    *(float4*)&Bs[bkr][bcq * 4] = bv;
    __syncthreads();
#pragma unroll
    for (int k = 0; k < 16; ++k) {
      float4 a = *(const float4*)&As[k][ty * 4];
      float4 b = *(const float4*)&Bs[k][tx * 4];
      acc[0][0] += a.x * b.x; acc[0][1] += a.x * b.y; acc[0][2] += a.x * b.z; acc[0][3] += a.x * b.w;
      acc[1][0] += a.y * b.x; acc[1][1] += a.y * b.y; acc[1][2] += a.y * b.z; acc[1][3] += a.y * b.w;
      acc[2][0] += a.z * b.x; acc[2][1] += a.z * b.y; acc[2][2] += a.z * b.z; acc[2][3] += a.z * b.w;
      acc[3][0] += a.w * b.x; acc[3][1] += a.w * b.y; acc[3][2] += a.w * b.z; acc[3][3] += a.w * b.w;
    }
  }
#pragma unroll
  for (int i = 0; i < 4; ++i) {
    int r = row0 + ty * 4 + i;
    if (r < M) {
      float4 v = make_float4(acc[i][0], acc[i][1], acc[i][2], acc[i][3]);
      *(float4*)&C[(size_t)r * GH + col0 + tx * 4] = v;
    }
  }
}

// ------------- GCN aggregation: gather + self-loop + bias + relu -------------
__global__ __launch_bounds__(256) void agg_kernel(const float* __restrict__ m,
                                                  const float* __restrict__ dinv,
                                                  const int* __restrict__ off,
                                                  const int* __restrict__ srcs,
                                                  const float* __restrict__ bias,
                                                  float* __restrict__ out) {
  int node = blockIdx.x * 4 + (threadIdx.x >> 6);
  if (node >= GN) return;
  int lane = threadIdx.x & 63;
  float4 acc = *(const float4*)&bias[lane * 4];
  float di = dinv[node];
  float w0 = di * di;  // self-loop norm
  float4 mv = *(const float4*)&m[(size_t)node * GH + lane * 4];
  acc.x += w0 * mv.x; acc.y += w0 * mv.y; acc.z += w0 * mv.z; acc.w += w0 * mv.w;
  int e0 = off[node], e1 = off[node + 1];
  int e = e0;
  for (; e + 2 <= e1; e += 2) {  // unroll-by-2: two row loads in flight
    int s0 = srcs[e], s1 = srcs[e + 1];
    float w0a = di * dinv[s0];
    float w1a = di * dinv[s1];
    float4 v0 = *(const float4*)&m[(size_t)s0 * GH + lane * 4];
    float4 v1 = *(const float4*)&m[(size_t)s1 * GH + lane * 4];
    acc.x += w0a * v0.x + w1a * v1.x;
    acc.y += w0a * v0.y + w1a * v1.y;
    acc.z += w0a * v0.z + w1a * v1.z;
    acc.w += w0a * v0.w + w1a * v1.w;
  }
  if (e < e1) {
    int s = srcs[e];
    float w = di * dinv[s];
    float4 v = *(const float4*)&m[(size_t)s * GH + lane * 4];
    acc.x += w * v.x; acc.y += w * v.y; acc.z += w * v.z; acc.w += w * v.w;
  }
  acc.x = fmaxf(acc.x, 0.f); acc.y = fmaxf(acc.y, 0.f);
  acc.z = fmaxf(acc.z, 0.f); acc.w = fmaxf(acc.w, 0.f);
  *(float4*)&out[(size_t)node * GH + lane * 4] = acc;
}

// ------- wavelet+pool v3: nonzero-parallel, fixed-trip loop, LDS seg accum -------
// grid (NCHB, NSLICE), block 256 = 8 groups x 32 lanes. LDS 48KB -> 3 blocks/CU.
// Each group walks a contiguous col-sorted nnz range: per nnz one broadcast 8B
// metadata load (L1), one 128B h load (L1-hot, consecutive nnz share cols), one
// conflict-free ds_add. Dense loop -> compiler unrolls -> MLP hides latency.
__global__ __launch_bounds__(256) void pooled3_kernel(const float* __restrict__ h,
                                                      const int2* __restrict__ pk,
                                                      float* __restrict__ pp) {
  __shared__ float acc[NSEG * SLW];  // 12288 floats = 48 KB
  int tid = threadIdx.x;
  int chunk = blockIdx.x, slice = blockIdx.y;
  for (int t = tid; t < NSEG * SLW; t += 256) acc[t] = 0.f;
  __syncthreads();
  int g = tid >> 5;   // group 0..7
  int f = tid & 31;   // feature within slice
  const float* hs = h + slice * SLW + f;
  int j0 = chunk * PPB;
  int j1 = j0 + PPB; if (j1 > GNNZ) j1 = GNNZ;
  const int sub = (PPB + 7) / 8;  // 1563
  int jg0 = j0 + g * sub;
  int jg1 = jg0 + sub; if (jg1 > j1) jg1 = j1;
  for (int j = jg0; j < jg1; ++j) {
    int2 m = pk[j];                       // broadcast across the 32-lane group
    int c = m.x & 0xFFFF;
    int s = m.x >> 16;
    float dv = __int_as_float(m.y);
    float hv = hs[(size_t)c * GH];        // 128B coalesced per group
    atomicAdd(&acc[s * SLW + f], dv * hv);  // ds_add_f32, 2 lanes/bank = free
  }
  __syncthreads();
  float* dst = &pp[((size_t)slice * NCHB + chunk) * (NSEG * SLW)];
  for (int t = tid; t < NSEG * SLW; t += 256) dst[t] = acc[t];
}

// reduce partials: pooled[seg][slice*SLW+f] = sum over chunks
__global__ __launch_bounds__(256) void pool_reduce_kernel(const float* __restrict__ pp,
                                                          float* __restrict__ pooled) {
  int seg = blockIdx.x;
  int tid = threadIdx.x;       // 256 feats; feature = slice*SLW + f = tid
  int slice = tid >> 5;
  int f = tid & 31;
  float v = 0.f;
  for (int ch = 0; ch < NCHB; ++ch) {
    v += pp[((size_t)slice * NCHB + ch) * (NSEG * SLW) + seg * SLW + f];
  }
  pooled[(size_t)seg * GH + tid] = v;
}

// ---------------- FC head ----------------
__global__ __launch_bounds__(256) void fc1_kernel(const float* __restrict__ pooled,
                                                  const float* __restrict__ w,
                                                  const float* __restrict__ b,
                                                  float* __restrict__ z1) {
  __shared__ float vin[GSCALE * GH];  // 768
  int g = blockIdx.x, tid = threadIdx.x;
#pragma unroll
  for (int it = 0; it < GSCALE; ++it)
    vin[it * GH + tid] = pooled[(size_t)(it * GB + g) * GH + tid];
  __syncthreads();
  float acc = b[tid];
  for (int j = 0; j < GSCALE * GH; ++j) acc += vin[j] * w[(size_t)j * GH + tid];
  z1[(size_t)g * GH + tid] = fmaxf(acc, 0.f);
}

__global__ __launch_bounds__(128) void fc2_kernel(const float* __restrict__ z1,
                                                  const float* __restrict__ w,
                                                  const float* __restrict__ b,
                                                  float* __restrict__ z2) {
  __shared__ float vin[GH];
  int g = blockIdx.x, tid = threadIdx.x;  // 128 threads
  vin[tid] = z1[(size_t)g * GH + tid];
  vin[128 + tid] = z1[(size_t)g * GH + 128 + tid];
  __syncthreads();
  float acc = b[tid];
  for (int j = 0; j < GH; ++j) acc += vin[j] * w[(size_t)j * 128 + tid];
  z2[(size_t)g * 128 + tid] = fmaxf(acc, 0.f);
}

__global__ __launch_bounds__(128) void fc3_kernel(const float* __restrict__ z2,
                                                  const float* __restrict__ w,
                                                  const float* __restrict__ b,
                                                  float* __restrict__ out) {
  int g = threadIdx.x;  // one thread per graph, 1 block of 128
  float logit[NCLS];
#pragma unroll
  for (int o = 0; o < NCLS; ++o) logit[o] = b[o];
  for (int k = 0; k < 128; ++k) {
    float zv = z2[(size_t)g * 128 + k];
#pragma unroll
    for (int o = 0; o < NCLS; ++o) logit[o] += zv * w[k * NCLS + o];
  }
  float mx = logit[0];
#pragma unroll
  for (int o = 1; o < NCLS; ++o) mx = fmaxf(mx, logit[o]);
  float lse = 0.f;
#pragma unroll
  for (int o = 0; o < NCLS; ++o) lse += expf(logit[o] - mx);
  lse = logf(lse);
#pragma unroll
  for (int o = 0; o < NCLS; ++o) out[(size_t)g * NCLS + o] = logit[o] - mx - lse;
}

// ---------------- launch ----------------
static inline size_t alignup(size_t x) { return (x + 1023) & ~(size_t)1023; }

extern "C" void kernel_launch(void* const* d_in, const int* in_sizes, int n_in,
                              void* d_out, int out_size, void* d_ws, size_t ws_size,
                              hipStream_t stream) {
  const float* x      = (const float*)d_in[0];
  const float* W1     = (const float*)d_in[1];
  const float* b1     = (const float*)d_in[2];
  const float* W2     = (const float*)d_in[3];
  const float* b2     = (const float*)d_in[4];
  const float* W3     = (const float*)d_in[5];
  const float* b3     = (const float*)d_in[6];
  const float* fc1w   = (const float*)d_in[7];
  const float* fc1b   = (const float*)d_in[8];
  const float* fc2w   = (const float*)d_in[9];
  const float* fc2b   = (const float*)d_in[10];
  const float* fc3w   = (const float*)d_in[11];
  const float* fc3b   = (const float*)d_in[12];
  const float* dval   = (const float*)d_in[13];
  const int* eidx     = (const int*)d_in[14];
  const int* batch    = (const int*)d_in[15];
  const int* didx     = (const int*)d_in[16];
  float* out          = (float*)d_out;

  const int* esrc = eidx;             // edge_index[0]
  const int* edst = eidx + GE;        // edge_index[1]
  const int* nzrow = didx;            // d_index[0]
  const int* nzcol = didx + GNNZ;     // d_index[1]

  // workspace carve-up
  char* ws = (char*)d_ws;
  size_t o = 0;
  auto take = [&](size_t bytes) { char* p = ws + o; o += alignup(bytes); return p; };
  int*   deg     = (int*)take(GN * 4);
  int*   off     = (int*)take((GN + 1) * 4);
  int*   cur     = (int*)take(GN * 4);
  int*   btot    = (int*)take(256 * 4);
  float* dinv    = (float*)take(GN * 4);
  int*   csr_src = (int*)take(GE * 4);
  int*   ccnt    = (int*)take(GN * 4);
  int*   coff    = (int*)take((GN + 1) * 4);
  int*   ccur    = (int*)take(GN * 4);
  int2*  pk      = (int2*)take((size_t)GNNZ * 8);
  float* mbuf    = (float*)take((size_t)GN * GH * 4);
  float* hA      = (float*)take((size_t)GN * GH * 4);
  float* hB      = (float*)take((size_t)GN * GH * 4);
  float* pooled  = (float*)take((size_t)NSEG * GH * 4);
  float* z1      = (float*)take((size_t)GB * GH * 4);
  float* z2      = (float*)take((size_t)GB * 128 * 4);
  float* pp      = mbuf;  // alias: partials (37.7 MB) live in mbuf, free after last agg
  (void)ws_size; (void)n_in; (void)in_sizes; (void)out_size;

  const int NB = (GN + 255) / 256;  // 196

  // ---- graph prep (once per call) ----
  hipMemsetAsync(deg, 0, GN * 4, stream);
  hipMemsetAsync(ccnt, 0, GN * 4, stream);

  deg_count_kernel<<<GE / 256, 256, 0, stream>>>(edst, deg);
  dinv_kernel<<<NB, 256, 0, stream>>>(deg, dinv);
  scan1_kernel<<<NB, 256, 0, stream>>>(deg, off, btot, GN);
  scan2_kernel<<<1, 256, 0, stream>>>(btot, NB);
  scan3_kernel<<<NB, 256, 0, stream>>>(off, btot, GN, GE);
  hipMemcpyAsync(cur, off, GN * 4, hipMemcpyDeviceToDevice, stream);
  csr_fill_kernel<<<GE / 256, 256, 0, stream>>>(esrc, edst, cur, csr_src);

  // col buckets for wavelet+pool (pk sorted by col)
  col_cnt_kernel<<<(GNNZ + 255) / 256, 256, 0, stream>>>(nzcol, ccnt);
  scan1_kernel<<<NB, 256, 0, stream>>>(ccnt, coff, btot, GN);
  scan2_kernel<<<1, 256, 0, stream>>>(btot, NB);
  scan3_kernel<<<NB, 256, 0, stream>>>(coff, btot, GN, GNNZ);
  hipMemcpyAsync(ccur, coff, GN * 4, hipMemcpyDeviceToDevice, stream);
  col_fill_kernel<<<(GNNZ + 255) / 256, 256, 0, stream>>>(nzrow, nzcol, dval, batch,
                                                          ccur, pk);

  // ---- 3 GCN layers ----
  dim3 ggrid(GH / 64, (GN + 63) / 64);
  gemm_kernel<FIN><<<ggrid, 256, 0, stream>>>(x, W1, mbuf, GN);
  agg_kernel<<<(GN + 3) / 4, 256, 0, stream>>>(mbuf, dinv, off, csr_src, b1, hA);
  gemm_kernel<GH><<<ggrid, 256, 0, stream>>>(hA, W2, mbuf, GN);
  agg_kernel<<<(GN + 3) / 4, 256, 0, stream>>>(mbuf, dinv, off, csr_src, b2, hB);
  gemm_kernel<GH><<<ggrid, 256, 0, stream>>>(hB, W3, mbuf, GN);
  agg_kernel<<<(GN + 3) / 4, 256, 0, stream>>>(mbuf, dinv, off, csr_src, b3, hA);

  // ---- fused wavelet + pooling (hA holds final node features; pp aliases mbuf) ----
  pooled3_kernel<<<dim3(NCHB, NSLICE), 256, 0, stream>>>(hA, pk, pp);
  pool_reduce_kernel<<<NSEG, 256, 0, stream>>>(pp, pooled);

  // ---- FC head ----
  fc1_kernel<<<GB, 256, 0, stream>>>(pooled, fc1w, fc1b, z1);
  fc2_kernel<<<GB, 128, 0, stream>>>(z1, fc2w, fc2b, z2);
  fc3_kernel<<<1, 128, 0, stream>>>(z2, fc3w, fc3b, out);
}

// Round 10
// 1141.541 us; speedup vs baseline: 2.2087x; 2.1938x over previous
//
#include <hip/hip_runtime.h>
#include <hip/hip_bf16.h>

#define GN 50000
#define GE 800000
#define FIN 128
#define GH 256
#define GB 128
#define NCLS 10
#define GSCALE 3
#define GNNZ 1200000
#define NSEG (GSCALE * GB)  // 384
#define PAD 16              // ints per counter slot (64B line) to kill false sharing

// ---------------- degree / dinv ----------------
__global__ __launch_bounds__(256) void deg_count_kernel(const int* __restrict__ dst,
                                                        int* __restrict__ deg) {
  int i = blockIdx.x * 256 + threadIdx.x;
  if (i < GE) atomicAdd(&deg[dst[i]], 1);
}

__global__ __launch_bounds__(256) void dinv_kernel(const int* __restrict__ deg,
                                                   float* __restrict__ dinv) {
  int i = blockIdx.x * 256 + threadIdx.x;
  if (i < GN) dinv[i] = 1.0f / sqrtf((float)(deg[i] + 1));  // self-loop => deg+1 >= 1
}

// ---------------- hierarchical exclusive scan (n up to GN) ----------------
__global__ __launch_bounds__(256) void scan1_kernel(const int* __restrict__ in,
                                                    int* __restrict__ out,
                                                    int* __restrict__ btot, int n) {
  __shared__ int sh[256];
  int b = blockIdx.x, tid = threadIdx.x;
  int i = b * 256 + tid;
  int v = (i < n) ? in[i] : 0;
  sh[tid] = v;
  __syncthreads();
  for (int ofs = 1; ofs < 256; ofs <<= 1) {
    int t = (tid >= ofs) ? sh[tid - ofs] : 0;
    __syncthreads();
    sh[tid] += t;
    __syncthreads();
  }
  if (i < n) out[i] = sh[tid] - v;  // block-local exclusive
  if (tid == 255) btot[b] = sh[255];
}

__global__ __launch_bounds__(256) void scan2_kernel(int* __restrict__ btot, int nb) {
  __shared__ int sh[256];
  int tid = threadIdx.x;
  int v = (tid < nb) ? btot[tid] : 0;
  sh[tid] = v;
  __syncthreads();
  for (int ofs = 1; ofs < 256; ofs <<= 1) {
    int t = (tid >= ofs) ? sh[tid - ofs] : 0;
    __syncthreads();
    sh[tid] += t;
    __syncthreads();
  }
  if (tid < nb) btot[tid] = sh[tid] - v;  // exclusive block bases
}

__global__ __launch_bounds__(256) void scan3_kernel(int* __restrict__ out,
                                                    const int* __restrict__ btot,
                                                    int n, int total) {
  int b = blockIdx.x, tid = threadIdx.x;
  int i = b * 256 + tid;
  if (i < n) out[i] += btot[b];
  if (i == 0) out[n] = total;
}

// ------------- small strided exclusive scan (n <= few hundred) -------------
__global__ __launch_bounds__(256) void exscan_strided_kernel(const int* __restrict__ in,
                                                             int* __restrict__ out,
                                                             int n, int stride) {
  __shared__ int sh[256];
  __shared__ int carry;
  int tid = threadIdx.x;
  if (tid == 0) carry = 0;
  __syncthreads();
  for (int base = 0; base < n; base += 256) {
    int i = base + tid;
    int v = (i < n) ? in[(size_t)i * stride] : 0;
    sh[tid] = v;
    __syncthreads();
    for (int ofs = 1; ofs < 256; ofs <<= 1) {
      int t = (tid >= ofs) ? sh[tid - ofs] : 0;
      __syncthreads();
      sh[tid] += t;
      __syncthreads();
    }
    if (i < n) out[i] = carry + sh[tid] - v;
    int total = sh[255];
    __syncthreads();
    if (tid == 0) carry += total;
    __syncthreads();
  }
  if (tid == 0) out[n] = carry;
}

// ---------------- CSR fill (bucket edges by dst) ----------------
__global__ __launch_bounds__(256) void csr_fill_kernel(const int* __restrict__ src,
                                                       const int* __restrict__ dst,
                                                       int* __restrict__ cur,
                                                       int* __restrict__ csr_src) {
  int i = blockIdx.x * 256 + threadIdx.x;
  if (i < GE) {
    int j = atomicAdd(&cur[dst[i]], 1);
    csr_src[j] = src[i];
  }
}

// ---------------- seg bucketing for wavelet+pool (PADDED counters) ----------------
__device__ __forceinline__ int seg_of(int row, const int* __restrict__ batch) {
  int sc = row / GN;
  int node = row - sc * GN;
  return sc * GB + batch[node];
}

__global__ __launch_bounds__(256) void seg_cnt_kernel(const int* __restrict__ rows,
                                                      const int* __restrict__ batch,
                                                      int* __restrict__ scnt_p) {
  int i = blockIdx.x * 256 + threadIdx.x;
  if (i < GNNZ) atomicAdd(&scnt_p[(size_t)seg_of(rows[i], batch) * PAD], 1);
}

__global__ __launch_bounds__(256) void scur_init_kernel(const int* __restrict__ soff,
                                                        int* __restrict__ scur_p) {
  int s = blockIdx.x * 256 + threadIdx.x;
  if (s < NSEG) scur_p[(size_t)s * PAD] = soff[s];
}

__global__ __launch_bounds__(256) void seg_fill_kernel(const int* __restrict__ rows,
                                                       const int* __restrict__ cols,
                                                       const float* __restrict__ d,
                                                       const int* __restrict__ batch,
                                                       int* __restrict__ scur_p,
                                                       int* __restrict__ scol,
                                                       float* __restrict__ sd) {
  int i = blockIdx.x * 256 + threadIdx.x;
  if (i < GNNZ) {
    int j = atomicAdd(&scur_p[(size_t)seg_of(rows[i], batch) * PAD], 1);
    scol[j] = cols[i];
    sd[j] = d[i];
  }
}

// ---------------- fp32 GEMM: C[M][256] = A[M][K] @ W[K][256] ----------------
template <int K>
__global__ __launch_bounds__(256) void gemm_kernel(const float* __restrict__ A,
                                                   const float* __restrict__ W,
                                                   float* __restrict__ C, int M) {
  __shared__ float As[16][64];  // As[k][r] = A[row0+r][kk+k]
  __shared__ float Bs[16][64];  // Bs[k][c] = W[kk+k][col0+c]
  int tid = threadIdx.x;
  int col0 = blockIdx.x * 64;
  int row0 = blockIdx.y * 64;
  float acc[4][4] = {};
  int ar = tid >> 2, akq = tid & 3;    // A stage: row ar, float4 group akq
  int bkr = tid >> 4, bcq = tid & 15;  // B stage
  int ty = tid >> 4, tx = tid & 15;
  for (int kk = 0; kk < K; kk += 16) {
    int arow = row0 + ar;
    if (arow >= M) arow = M - 1;
    float4 av = *(const float4*)&A[(size_t)arow * K + kk + akq * 4];
    float4 bv = *(const float4*)&W[(size_t)(kk + bkr) * GH + col0 + bcq * 4];
    __syncthreads();
    As[akq * 4 + 0][ar] = av.x;
    As[akq * 4 + 1][ar] = av.y;
    As[akq * 4 + 2][ar] = av.z;
    As[akq * 4 + 3][ar] = av.w;
    *(float4*)&Bs[bkr][bcq * 4] = bv;
    __syncthreads();
#pragma unroll
    for (int k = 0; k < 16; ++k) {
      float4 a = *(const float4*)&As[k][ty * 4];
      float4 b = *(const float4*)&Bs[k][tx * 4];
      acc[0][0] += a.x * b.x; acc[0][1] += a.x * b.y; acc[0][2] += a.x * b.z; acc[0][3] += a.x * b.w;
      acc[1][0] += a.y * b.x; acc[1][1] += a.y * b.y; acc[1][2] += a.y * b.z; acc[1][3] += a.y * b.w;
      acc[2][0] += a.z * b.x; acc[2][1] += a.z * b.y; acc[2][2] += a.z * b.z; acc[2][3] += a.z * b.w;
      acc[3][0] += a.w * b.x; acc[3][1] += a.w * b.y; acc[3][2] += a.w * b.z; acc[3][3] += a.w * b.w;
    }
  }
#pragma unroll
  for (int i = 0; i < 4; ++i) {
    int r = row0 + ty * 4 + i;
    if (r < M) {
      float4 v = make_float4(acc[i][0], acc[i][1], acc[i][2], acc[i][3]);
      *(float4*)&C[(size_t)r * GH + col0 + tx * 4] = v;
    }
  }
}

// ------------- GCN aggregation: gather + self-loop + bias + relu -------------
__global__ __launch_bounds__(256) void agg_kernel(const float* __restrict__ m,
                                                  const float* __restrict__ dinv,
                                                  const int* __restrict__ off,
                                                  const int* __restrict__ srcs,
                                                  const float* __restrict__ bias,
                                                  float* __restrict__ out) {
  int node = blockIdx.x * 4 + (threadIdx.x >> 6);
  if (node >= GN) return;
  int lane = threadIdx.x & 63;
  float4 acc = *(const float4*)&bias[lane * 4];
  float di = dinv[node];
  float w0 = di * di;  // self-loop norm
  float4 mv = *(const float4*)&m[(size_t)node * GH + lane * 4];
  acc.x += w0 * mv.x; acc.y += w0 * mv.y; acc.z += w0 * mv.z; acc.w += w0 * mv.w;
  int e0 = off[node], e1 = off[node + 1];
  int e = e0;
  for (; e + 2 <= e1; e += 2) {  // unroll-by-2: two row loads in flight
    int s0 = srcs[e], s1 = srcs[e + 1];
    float w0a = di * dinv[s0];
    float w1a = di * dinv[s1];
    float4 v0 = *(const float4*)&m[(size_t)s0 * GH + lane * 4];
    float4 v1 = *(const float4*)&m[(size_t)s1 * GH + lane * 4];
    acc.x += w0a * v0.x + w1a * v1.x;
    acc.y += w0a * v0.y + w1a * v1.y;
    acc.z += w0a * v0.z + w1a * v1.z;
    acc.w += w0a * v0.w + w1a * v1.w;
  }
  if (e < e1) {
    int s = srcs[e];
    float w = di * dinv[s];
    float4 v = *(const float4*)&m[(size_t)s * GH + lane * 4];
    acc.x += w * v.x; acc.y += w * v.y; acc.z += w * v.z; acc.w += w * v.w;
  }
  acc.x = fmaxf(acc.x, 0.f); acc.y = fmaxf(acc.y, 0.f);
  acc.z = fmaxf(acc.z, 0.f); acc.w = fmaxf(acc.w, 0.f);
  *(float4*)&out[(size_t)node * GH + lane * 4] = acc;
}

// ------- fused wavelet transform + per-(scale,graph) pooling gather -------
// MEASURED 162 us (r2). Staged 256-nnz chunks -> fixed-trip inner loop gives the
// compiler 256 independent h-row loads to pipeline (latency-tolerant). The
// read-once LDS-scatter variants (r7/r9) collapsed to ~1.5 ms: dependent
// pk->h->ds_add chains get NO compiler MLP. Do not retry without explicit
// register-batched prefetch.
__global__ __launch_bounds__(256) void pooled_kernel(const float* __restrict__ h,
                                                     const int* __restrict__ soff,
                                                     const int* __restrict__ scol,
                                                     const float* __restrict__ sd,
                                                     float* __restrict__ pooled) {
  __shared__ int lcol[256];
  __shared__ float ld[256];
  int seg = blockIdx.x;
  int j0 = soff[seg], j1 = soff[seg + 1];
  int cnt = j1 - j0;
  int nparts = gridDim.y;
  int per = (cnt + nparts - 1) / nparts;
  int s = j0 + blockIdx.y * per;
  int e = s + per;
  if (e > j1) e = j1;
  int tid = threadIdx.x;
  float acc = 0.f;
  for (int base = s; base < e; base += 256) {
    int nload = e - base;
    if (nload > 256) nload = 256;
    __syncthreads();
    if (tid < nload) {
      lcol[tid] = scol[base + tid];
      ld[tid] = sd[base + tid];
    }
    __syncthreads();
    for (int t = 0; t < nload; ++t) {
      acc += ld[t] * h[(size_t)lcol[t] * GH + tid];
    }
  }
  atomicAdd(&pooled[(size_t)seg * GH + tid], acc);
}

// ---------------- FC head ----------------
__global__ __launch_bounds__(256) void fc1_kernel(const float* __restrict__ pooled,
                                                  const float* __restrict__ w,
                                                  const float* __restrict__ b,
                                                  float* __restrict__ z1) {
  __shared__ float vin[GSCALE * GH];  // 768
  int g = blockIdx.x, tid = threadIdx.x;
#pragma unroll
  for (int it = 0; it < GSCALE; ++it)
    vin[it * GH + tid] = pooled[(size_t)(it * GB + g) * GH + tid];
  __syncthreads();
  float acc = b[tid];
  for (int j = 0; j < GSCALE * GH; ++j) acc += vin[j] * w[(size_t)j * GH + tid];
  z1[(size_t)g * GH + tid] = fmaxf(acc, 0.f);
}

__global__ __launch_bounds__(128) void fc2_kernel(const float* __restrict__ z1,
                                                  const float* __restrict__ w,
                                                  const float* __restrict__ b,
                                                  float* __restrict__ z2) {
  __shared__ float vin[GH];
  int g = blockIdx.x, tid = threadIdx.x;  // 128 threads
  vin[tid] = z1[(size_t)g * GH + tid];
  vin[128 + tid] = z1[(size_t)g * GH + 128 + tid];
  __syncthreads();
  float acc = b[tid];
  for (int j = 0; j < GH; ++j) acc += vin[j] * w[(size_t)j * 128 + tid];
  z2[(size_t)g * 128 + tid] = fmaxf(acc, 0.f);
}

__global__ __launch_bounds__(128) void fc3_kernel(const float* __restrict__ z2,
                                                  const float* __restrict__ w,
                                                  const float* __restrict__ b,
                                                  float* __restrict__ out) {
  int g = threadIdx.x;  // one thread per graph, 1 block of 128
  float logit[NCLS];
#pragma unroll
  for (int o = 0; o < NCLS; ++o) logit[o] = b[o];
  for (int k = 0; k < 128; ++k) {
    float zv = z2[(size_t)g * 128 + k];
#pragma unroll
    for (int o = 0; o < NCLS; ++o) logit[o] += zv * w[k * NCLS + o];
  }
  float mx = logit[0];
#pragma unroll
  for (int o = 1; o < NCLS; ++o) mx = fmaxf(mx, logit[o]);
  float lse = 0.f;
#pragma unroll
  for (int o = 0; o < NCLS; ++o) lse += expf(logit[o] - mx);
  lse = logf(lse);
#pragma unroll
  for (int o = 0; o < NCLS; ++o) out[(size_t)g * NCLS + o] = logit[o] - mx - lse;
}

// ---------------- launch ----------------
static inline size_t alignup(size_t x) { return (x + 1023) & ~(size_t)1023; }

extern "C" void kernel_launch(void* const* d_in, const int* in_sizes, int n_in,
                              void* d_out, int out_size, void* d_ws, size_t ws_size,
                              hipStream_t stream) {
  const float* x      = (const float*)d_in[0];
  const float* W1     = (const float*)d_in[1];
  const float* b1     = (const float*)d_in[2];
  const float* W2     = (const float*)d_in[3];
  const float* b2     = (const float*)d_in[4];
  const float* W3     = (const float*)d_in[5];
  const float* b3     = (const float*)d_in[6];
  const float* fc1w   = (const float*)d_in[7];
  const float* fc1b   = (const float*)d_in[8];
  const float* fc2w   = (const float*)d_in[9];
  const float* fc2b   = (const float*)d_in[10];
  const float* fc3w   = (const float*)d_in[11];
  const float* fc3b   = (const float*)d_in[12];
  const float* dval   = (const float*)d_in[13];
  const int* eidx     = (const int*)d_in[14];
  const int* batch    = (const int*)d_in[15];
  const int* didx     = (const int*)d_in[16];
  float* out          = (float*)d_out;

  const int* esrc = eidx;             // edge_index[0]
  const int* edst = eidx + GE;        // edge_index[1]
  const int* nzrow = didx;            // d_index[0]
  const int* nzcol = didx + GNNZ;     // d_index[1]

  // workspace carve-up
  char* ws = (char*)d_ws;
  size_t o = 0;
  auto take = [&](size_t bytes) { char* p = ws + o; o += alignup(bytes); return p; };
  int*   deg     = (int*)take(GN * 4);
  int*   off     = (int*)take((GN + 1) * 4);
  int*   cur     = (int*)take(GN * 4);
  int*   btot    = (int*)take(256 * 4);
  float* dinv    = (float*)take(GN * 4);
  int*   csr_src = (int*)take(GE * 4);
  int*   scnt_p  = (int*)take(NSEG * PAD * 4);
  int*   soff    = (int*)take((NSEG + 1) * 4);
  int*   scur_p  = (int*)take(NSEG * PAD * 4);
  int*   scol    = (int*)take((size_t)GNNZ * 4);
  float* sd      = (float*)take((size_t)GNNZ * 4);
  float* mbuf    = (float*)take((size_t)GN * GH * 4);
  float* hA      = (float*)take((size_t)GN * GH * 4);
  float* hB      = (float*)take((size_t)GN * GH * 4);
  float* pooled  = (float*)take((size_t)NSEG * GH * 4);
  float* z1      = (float*)take((size_t)GB * GH * 4);
  float* z2      = (float*)take((size_t)GB * 128 * 4);
  (void)ws_size; (void)n_in; (void)in_sizes; (void)out_size;

  const int NB = (GN + 255) / 256;  // 196

  // ---- graph prep (once per call) ----
  hipMemsetAsync(deg, 0, GN * 4, stream);
  hipMemsetAsync(scnt_p, 0, NSEG * PAD * 4, stream);
  hipMemsetAsync(pooled, 0, (size_t)NSEG * GH * 4, stream);

  deg_count_kernel<<<GE / 256, 256, 0, stream>>>(edst, deg);
  dinv_kernel<<<NB, 256, 0, stream>>>(deg, dinv);
  scan1_kernel<<<NB, 256, 0, stream>>>(deg, off, btot, GN);
  scan2_kernel<<<1, 256, 0, stream>>>(btot, NB);
  scan3_kernel<<<NB, 256, 0, stream>>>(off, btot, GN, GE);
  hipMemcpyAsync(cur, off, GN * 4, hipMemcpyDeviceToDevice, stream);
  csr_fill_kernel<<<GE / 256, 256, 0, stream>>>(esrc, edst, cur, csr_src);

  seg_cnt_kernel<<<(GNNZ + 255) / 256, 256, 0, stream>>>(nzrow, batch, scnt_p);
  exscan_strided_kernel<<<1, 256, 0, stream>>>(scnt_p, soff, NSEG, PAD);
  scur_init_kernel<<<(NSEG + 255) / 256, 256, 0, stream>>>(soff, scur_p);
  seg_fill_kernel<<<(GNNZ + 255) / 256, 256, 0, stream>>>(nzrow, nzcol, dval, batch,
                                                          scur_p, scol, sd);

  // ---- 3 GCN layers ----
  dim3 ggrid(GH / 64, (GN + 63) / 64);
  gemm_kernel<FIN><<<ggrid, 256, 0, stream>>>(x, W1, mbuf, GN);
  agg_kernel<<<(GN + 3) / 4, 256, 0, stream>>>(mbuf, dinv, off, csr_src, b1, hA);
  gemm_kernel<GH><<<ggrid, 256, 0, stream>>>(hA, W2, mbuf, GN);
  agg_kernel<<<(GN + 3) / 4, 256, 0, stream>>>(mbuf, dinv, off, csr_src, b2, hB);
  gemm_kernel<GH><<<ggrid, 256, 0, stream>>>(hB, W3, mbuf, GN);
  agg_kernel<<<(GN + 3) / 4, 256, 0, stream>>>(mbuf, dinv, off, csr_src, b3, hA);

  // ---- fused wavelet + pooling (hA holds final node features) ----
  pooled_kernel<<<dim3(NSEG, 8), 256, 0, stream>>>(hA, soff, scol, sd, pooled);

  // ---- FC head ----
  fc1_kernel<<<GB, 256, 0, stream>>>(pooled, fc1w, fc1b, z1);
  fc2_kernel<<<GB, 128, 0, stream>>>(z1, fc2w, fc2b, z2);
  fc3_kernel<<<1, 128, 0, stream>>>(z2, fc3w, fc3b, out);
}